// Round 7
// baseline (186.155 us; speedup 1.0000x reference)
//
#include <hip/hip_runtime.h>
#include <cstdint>

#define NB1 8192
#define NB2 8192
#define DDIM 128
#define KROW 256           // stored row: [hi(128) | lo(128)] f16
#define NKITER 12          // virtual K = 384 (hi*hi + lo*hi + hi*lo), BK=32

using half8   = __attribute__((ext_vector_type(8))) _Float16;
using half4   = __attribute__((ext_vector_type(4))) _Float16;
using float4v = __attribute__((ext_vector_type(4))) float;

typedef __attribute__((address_space(3))) void       lds_void;
typedef const __attribute__((address_space(1))) void glb_void;

__device__ inline unsigned long long packkey(float v, int j) {
  unsigned u = __float_as_uint(v);
  u = (u & 0x80000000u) ? ~u : (u | 0x80000000u);  // monotone float->uint
  return ((unsigned long long)u << 32) | (unsigned)j;
}

// virtual kt -> source 32-f16 chunk index within the [hi|lo] row
__device__ __forceinline__ int a_src(int kt) { return (kt < 8) ? kt : kt - 8; } // hi,lo,hi
__device__ __forceinline__ int b_src(int kt) { return (kt < 4) ? kt : kt - 4; } // hi,hi,lo

// ---------------------------------------------------------------------------
// Kernel 0: fp32 -> f16 hi/lo split + squared norms + init packed keys + cnt.
// One wave per 2 rows; float4 loads, half4 stores.
// ---------------------------------------------------------------------------
__global__ __launch_bounds__(256) void convert_kernel(
    const float* __restrict__ d1, const float* __restrict__ d2,
    _Float16* __restrict__ A2, _Float16* __restrict__ B2,
    float* __restrict__ asq, float* __restrict__ bsq,
    unsigned long long* __restrict__ packed, int* __restrict__ cnt) {
  int gid  = blockIdx.x * 256 + threadIdx.x;
  int wv   = gid >> 6;
  int lane = gid & 63;
  int rowc = 2 * wv + (lane >> 5);
  bool isA = rowc < NB1;
  const float* src = isA ? d1 : d2;
  int row = isA ? rowc : rowc - NB1;
  int k4  = (lane & 31) * 4;

  float4 v = *(const float4*)&src[row * DDIM + k4];
  _Float16 h0 = (_Float16)v.x, h1 = (_Float16)v.y;
  _Float16 h2 = (_Float16)v.z, h3 = (_Float16)v.w;
  half4 hh = {h0, h1, h2, h3};
  half4 ll = {(_Float16)(v.x - (float)h0), (_Float16)(v.y - (float)h1),
              (_Float16)(v.z - (float)h2), (_Float16)(v.w - (float)h3)};

  _Float16* dst = (isA ? A2 : B2) + (size_t)row * KROW;
  *(half4*)&dst[k4]       = hh;
  *(half4*)&dst[128 + k4] = ll;

  float s = v.x * v.x + v.y * v.y + v.z * v.z + v.w * v.w;
  #pragma unroll
  for (int off = 16; off > 0; off >>= 1) s += __shfl_xor(s, off, 64);
  if ((lane & 31) == 0) (isA ? asq : bsq)[row] = s;

  if (gid < NB1) packed[gid] = 0xFFFFFFFFFFFFFFFFull;  // +inf key
  if (gid < NB1 / 128) cnt[gid] = 0;                   // strip arrival counters
}

// ---------------------------------------------------------------------------
// Kernel 1: MFMA GEMM (virtual K=384 f16, fp32 acc) + fused argmin + output.
// R5-proven core: 128x128 tile, BK=32 (12 barriers, 16 MFMA each), 34816 B
// LDS double-buffer -> ~3 waves/SIMD occupancy (the R6 BK=64/64KB variant
// dropped to 2 blocks/CU and regressed 67->124 us; do not enlarge LDS).
// - XCD swizzle: per-XCD resident set ~2 MB < 4 MB L2 (FETCH 18.6 MB, verified).
// - LDS cell (row r, chunk q) at 4r + ((q + (r>>1)) & 3): conflict-free
//   (verified SQ_LDS_BANK_CONFLICT = 0); staging fetches inverse-permuted chunk.
// - Epilogue: register fold -> pad-17 LDS lex-min -> device atomicMin(packed).
// - Last block per row-strip (threadfence + cnt) decodes packed via no-op
//   atomicMin reads and writes final outputs (no separate out_kernel;
//   correctness verified in R6, absmax 0.0).
// ---------------------------------------------------------------------------
__global__ __launch_bounds__(256, 3) void mfma_match_kernel(
    const _Float16* __restrict__ A2, const _Float16* __restrict__ B2,
    const float* __restrict__ asq, const float* __restrict__ bsq,
    unsigned long long* __restrict__ packed, int* __restrict__ cnt,
    float* __restrict__ out) {
  __shared__ unsigned long long smem[2 * 128 * 17];  // 34816 B, aliased
  __shared__ int flagp;
  _Float16* Asb = (_Float16*)smem;                   // 2 buffers x 4096 f16
  _Float16* Bsb = (_Float16*)smem + 8192;            // 2 buffers x 4096 f16

  const int t    = threadIdx.x;
  const int lane = t & 63;
  const int wid  = t >> 6;
  const int wm = wid >> 1, wn = wid & 1;
  const int lx = lane & 15, q = lane >> 4;

  // L2/XCD locality swizzle (dispatch round-robins id%8 across XCDs).
  const int id = blockIdx.x;
  const int xc = id & 7, kk = id >> 3;
  const int bx = ((kk >> 3) & 7) * 8 + xc;
  const int by = (kk & 7) + ((kk >> 6) & 7) * 8;
  const int row0 = bx * 128, col0 = by * 128;

  // Staging lane geometry. Slab = 16 rows x 4 cells(16B). Wave stages slabs
  // {2*wid, 2*wid+1}. Lane l -> row l>>2, LDS slot l&3; global chunk for that
  // slot is the inverse bank-swizzle: q = (slot - (row>>1)) & 3.
  const int sA   = wid * 2;
  const int rloc = lane >> 2;
  const int qch  = ((lane & 3) - (rloc >> 1)) & 3;
  const int rA0  = sA * 16 + rloc;
  const int kofs = qch * 8;

  float4v acc[4][4];
  #pragma unroll
  for (int r = 0; r < 4; ++r)
    #pragma unroll
    for (int c = 0; c < 4; ++c) acc[r][c] = (float4v){0.f, 0.f, 0.f, 0.f};

  float bq[4]; int jc[4];
  #pragma unroll
  for (int c = 0; c < 4; ++c) {
    jc[c] = col0 + wn * 64 + 16 * c + lx;
    bq[c] = bsq[jc[c]];
  }

  auto stage = [&](int kt, int buf) {
    const _Float16* ga =
        A2 + (size_t)(row0 + rA0) * KROW + a_src(kt) * 32 + kofs;
    __builtin_amdgcn_global_load_lds((glb_void*)ga,
        (lds_void*)(Asb + buf * 4096 + sA * 512), 16, 0, 0);
    __builtin_amdgcn_global_load_lds((glb_void*)(ga + 16 * KROW),
        (lds_void*)(Asb + buf * 4096 + (sA + 1) * 512), 16, 0, 0);
    const _Float16* gb =
        B2 + (size_t)(col0 + rA0) * KROW + b_src(kt) * 32 + kofs;
    __builtin_amdgcn_global_load_lds((glb_void*)gb,
        (lds_void*)(Bsb + buf * 4096 + sA * 512), 16, 0, 0);
    __builtin_amdgcn_global_load_lds((glb_void*)(gb + 16 * KROW),
        (lds_void*)(Bsb + buf * 4096 + (sA + 1) * 512), 16, 0, 0);
  };

  stage(0, 0);

  const int sw = ((q + (lx >> 1)) & 3) * 8;   // bank-swizzled chunk offset

  #pragma unroll
  for (int kt = 0; kt < NKITER; ++kt) {
    __syncthreads();  // stage(kt) drained (vmcnt0 before barrier); WAR safe
    if (kt < NKITER - 1) stage(kt + 1, (kt + 1) & 1);
    const _Float16* Ab = Asb + (kt & 1) * 4096;
    const _Float16* Bb = Bsb + (kt & 1) * 4096;
    half8 af[4], bf[4];
    #pragma unroll
    for (int r = 0; r < 4; ++r)
      af[r] = *(const half8*)&Ab[(wm * 64 + 16 * r + lx) * 32 + sw];
    #pragma unroll
    for (int c = 0; c < 4; ++c)
      bf[c] = *(const half8*)&Bb[(wn * 64 + 16 * c + lx) * 32 + sw];
    #pragma unroll
    for (int r = 0; r < 4; ++r)
      #pragma unroll
      for (int c = 0; c < 4; ++c)
        acc[r][c] = __builtin_amdgcn_mfma_f32_16x16x32_f16(
            af[r], bf[c], acc[r][c], 0, 0, 0);
  }

  // ---- Epilogue. C/D layout: col = lane&15, row = q*4 + reg. ----
  __syncthreads();  // all frag reads done before aliasing staging LDS
  #pragma unroll
  for (int r = 0; r < 4; ++r) {
    #pragma unroll
    for (int reg = 0; reg < 4; ++reg) {
      float bv = 1e30f; int bj = 0;
      #pragma unroll
      for (int c = 0; c < 4; ++c) {  // jc ascending -> strict < keeps min j
        float val = fmaf(-2.f, acc[r][c][reg], bq[c]);
        if (val < bv) { bv = val; bj = jc[c]; }
      }
      int mrow = wm * 64 + 16 * r + 4 * q + reg;
      smem[(wn * 128 + mrow) * 17 + lx] = packkey(bv, bj);
    }
  }
  __syncthreads();
  if (t < 128) {
    unsigned long long best = ~0ull;
    #pragma unroll
    for (int w = 0; w < 2; ++w)
      #pragma unroll
      for (int x = 0; x < 16; ++x) {
        unsigned long long k = smem[(w * 128 + t) * 17 + x];
        if (k < best) best = k;
      }
    atomicMin(&packed[row0 + t], best);  // device-scope lex (val, idx) min
  }

  // ---- Last block of this row-strip decodes + writes outputs. ----
  __syncthreads();  // per-wave vmcnt(0): this block's atomics retired
  if (t == 0) {
    __threadfence();
    flagp = (atomicAdd(&cnt[bx], 1) == NB2 / 128 - 1);
  }
  __syncthreads();
  if (flagp && t < 128) {
    int r = row0 + t;
    unsigned long long best = atomicMin(&packed[r], ~0ull);  // coherent read
    unsigned u = (unsigned)(best >> 32);
    u = (u & 0x80000000u) ? (u & 0x7fffffffu) : ~u;  // invert monotone map
    float dist = sqrtf(fmaxf(asq[r] + __uint_as_float(u), 0.f));
    int j = (int)(unsigned)(best & 0xffffffffu);
    out[r] = dist;
    float2 mi = {(float)r, (float)j};
    *(float2*)&out[NB1 + 2 * r] = mi;
  }
}

extern "C" void kernel_launch(void* const* d_in, const int* in_sizes, int n_in,
                              void* d_out, int out_size, void* d_ws, size_t ws_size,
                              hipStream_t stream) {
  const float* d1 = (const float*)d_in[0];
  const float* d2 = (const float*)d_in[1];
  float* out = (float*)d_out;

  char* w = (char*)d_ws;
  float* asq = (float*)w;                                   // 32 KB
  float* bsq = (float*)(w + 32768);                         // 32 KB
  _Float16* A2 = (_Float16*)(w + 65536);                    // 4 MB
  _Float16* B2 = (_Float16*)(w + 65536 + 4194304);          // 4 MB
  unsigned long long* packed =
      (unsigned long long*)(w + 65536 + 2 * 4194304);       // 64 KB
  int* cnt = (int*)(w + 65536 + 2 * 4194304 + 65536);       // 256 B

  convert_kernel<<<(NB1 + NB2) / 8, 256, 0, stream>>>(
      d1, d2, A2, B2, asq, bsq, packed, cnt);

  mfma_match_kernel<<<(NB1 / 128) * (NB2 / 128), 256, 0, stream>>>(
      A2, B2, asq, bsq, packed, cnt, out);
}

// Round 8
// 129.239 us; speedup vs baseline: 1.4404x; 1.4404x over previous
//
#include <hip/hip_runtime.h>
#include <cstdint>

#define NB1 8192
#define NB2 8192
#define DDIM 128
#define KROW 256           // stored row: [hi(128) | lo(128)] f16
#define NKITER 12          // virtual K = 384 (hi*hi + lo*hi + hi*lo), BK=32
#define CTILES 2           // column tiles of 128 per block
#define NSTRIPB (NB2 / (128 * CTILES))   // 32 blocks per row-strip

using half8   = __attribute__((ext_vector_type(8))) _Float16;
using half4   = __attribute__((ext_vector_type(4))) _Float16;
using float4v = __attribute__((ext_vector_type(4))) float;

typedef __attribute__((address_space(3))) void       lds_void;
typedef const __attribute__((address_space(1))) void glb_void;

__device__ inline unsigned long long packkey(float v, int j) {
  unsigned u = __float_as_uint(v);
  u = (u & 0x80000000u) ? ~u : (u | 0x80000000u);  // monotone float->uint
  return ((unsigned long long)u << 32) | (unsigned)j;
}

// virtual kt -> source 32-f16 chunk index within the [hi|lo] row
__device__ __forceinline__ int a_src(int kt) { return (kt < 8) ? kt : kt - 8; } // hi,lo,hi
__device__ __forceinline__ int b_src(int kt) { return (kt < 4) ? kt : kt - 4; } // hi,hi,lo

// ---------------------------------------------------------------------------
// Kernel 0: fp32 -> f16 hi/lo split + squared norms + init packed keys + cnt.
// ---------------------------------------------------------------------------
__global__ __launch_bounds__(256) void convert_kernel(
    const float* __restrict__ d1, const float* __restrict__ d2,
    _Float16* __restrict__ A2, _Float16* __restrict__ B2,
    float* __restrict__ asq, float* __restrict__ bsq,
    unsigned long long* __restrict__ packed, int* __restrict__ cnt) {
  int gid  = blockIdx.x * 256 + threadIdx.x;
  int wv   = gid >> 6;
  int lane = gid & 63;
  int rowc = 2 * wv + (lane >> 5);
  bool isA = rowc < NB1;
  const float* src = isA ? d1 : d2;
  int row = isA ? rowc : rowc - NB1;
  int k4  = (lane & 31) * 4;

  float4 v = *(const float4*)&src[row * DDIM + k4];
  _Float16 h0 = (_Float16)v.x, h1 = (_Float16)v.y;
  _Float16 h2 = (_Float16)v.z, h3 = (_Float16)v.w;
  half4 hh = {h0, h1, h2, h3};
  half4 ll = {(_Float16)(v.x - (float)h0), (_Float16)(v.y - (float)h1),
              (_Float16)(v.z - (float)h2), (_Float16)(v.w - (float)h3)};

  _Float16* dst = (isA ? A2 : B2) + (size_t)row * KROW;
  *(half4*)&dst[k4]       = hh;
  *(half4*)&dst[128 + k4] = ll;

  float s = v.x * v.x + v.y * v.y + v.z * v.z + v.w * v.w;
  #pragma unroll
  for (int off = 16; off > 0; off >>= 1) s += __shfl_xor(s, off, 64);
  if ((lane & 31) == 0) (isA ? asq : bsq)[row] = s;

  if (gid < NB1) packed[gid] = 0xFFFFFFFFFFFFFFFFull;  // +inf key
  if (gid < NB1 / 128) cnt[gid] = 0;                   // strip arrival counters
}

// ---------------------------------------------------------------------------
// Kernel 1: MFMA GEMM (virtual K=384 f16, fp32 acc) + fused argmin + output.
// R5-proven core: 128x128 tile, BK=32, 34816 B LDS dbuf (~3 waves/SIMD;
// R6's 64 KB variant regressed). CTILES=2: each block does two col-tiles,
// amortizing prologue/epilogue and halving packed atomics.
// - XCD swizzle: per-XCD resident ~1.5 MB (8 A-strips + 8 B-pairs) < 4 MB L2.
// - LDS cell (row r, chunk q) at 4r + ((q + (r>>1)) & 3): conflict-free
//   (verified SQ_LDS_BANK_CONFLICT = 0).
// - Epilogue: per-ct register fold -> pad-17 LDS lex-min -> atomicMin(packed).
// - Fused output WITHOUT __threadfence (R7 lesson: per-block agent fence
//   invalidates per-XCD L2 -> 2x regression). Ordering instead: atomicMin is
//   a vm-op, __syncthreads emits s_waitcnt vmcnt(0) per wave, so every
//   block's mins are globally performed before its cnt atomicAdd issues.
//   All cross-block data (packed, cnt) flows through device-scope atomics.
// ---------------------------------------------------------------------------
__global__ __launch_bounds__(256, 3) void mfma_match_kernel(
    const _Float16* __restrict__ A2, const _Float16* __restrict__ B2,
    const float* __restrict__ asq, const float* __restrict__ bsq,
    unsigned long long* __restrict__ packed, int* __restrict__ cnt,
    float* __restrict__ out) {
  __shared__ unsigned long long smem[2 * 128 * 17];  // 34816 B, aliased
  __shared__ int flagp;
  _Float16* Asb = (_Float16*)smem;                   // 2 buffers x 4096 f16
  _Float16* Bsb = (_Float16*)smem + 8192;            // 2 buffers x 4096 f16

  const int t    = threadIdx.x;
  const int lane = t & 63;
  const int wid  = t >> 6;
  const int wm = wid >> 1, wn = wid & 1;
  const int lx = lane & 15, q = lane >> 4;

  // XCD swizzle for 2048 blocks: xc = id&7, kk = id>>3 (0..255).
  // bx = ((kk>>3)&7)*8 + xc (0..63); byp = (kk&7) + ((kk>>6)&3)*8 (0..31).
  const int id = blockIdx.x;
  const int xc = id & 7, kk = id >> 3;
  const int bx  = ((kk >> 3) & 7) * 8 + xc;
  const int byp = (kk & 7) + ((kk >> 6) & 3) * 8;
  const int row0    = bx * 128;
  const int colbase = byp * (128 * CTILES);

  // Staging lane geometry. Slab = 16 rows x 4 cells(16B). Wave stages slabs
  // {2*wid, 2*wid+1}. Lane l -> row l>>2, LDS slot l&3; global chunk for that
  // slot is the inverse bank-swizzle: (slot - (row>>1)) & 3.
  const int sA   = wid * 2;
  const int rloc = lane >> 2;
  const int qch  = ((lane & 3) - (rloc >> 1)) & 3;
  const int rA0  = sA * 16 + rloc;
  const int kofs = qch * 8;

  float4v acc[4][4];
  #pragma unroll
  for (int r = 0; r < 4; ++r)
    #pragma unroll
    for (int c = 0; c < 4; ++c) acc[r][c] = (float4v){0.f, 0.f, 0.f, 0.f};

  float bestv[16];
  int   bestj[16];
  #pragma unroll
  for (int s = 0; s < 16; ++s) { bestv[s] = 1e30f; bestj[s] = 0; }

  auto stage = [&](int ct, int kt, int buf) {
    const _Float16* ga =
        A2 + (size_t)(row0 + rA0) * KROW + a_src(kt) * 32 + kofs;
    __builtin_amdgcn_global_load_lds((glb_void*)ga,
        (lds_void*)(Asb + buf * 4096 + sA * 512), 16, 0, 0);
    __builtin_amdgcn_global_load_lds((glb_void*)(ga + 16 * KROW),
        (lds_void*)(Asb + buf * 4096 + (sA + 1) * 512), 16, 0, 0);
    const _Float16* gb =
        B2 + (size_t)(colbase + ct * 128 + rA0) * KROW + b_src(kt) * 32 + kofs;
    __builtin_amdgcn_global_load_lds((glb_void*)gb,
        (lds_void*)(Bsb + buf * 4096 + sA * 512), 16, 0, 0);
    __builtin_amdgcn_global_load_lds((glb_void*)(gb + 16 * KROW),
        (lds_void*)(Bsb + buf * 4096 + (sA + 1) * 512), 16, 0, 0);
  };

  stage(0, 0, 0);

  const int sw = ((q + (lx >> 1)) & 3) * 8;   // bank-swizzled chunk offset

  #pragma unroll
  for (int ct = 0; ct < CTILES; ++ct) {
    #pragma unroll
    for (int kt = 0; kt < NKITER; ++kt) {
      const int ktg = ct * NKITER + kt;
      __syncthreads();  // stage(ktg) drained (vmcnt0 before barrier); WAR safe
      if (kt < NKITER - 1)      stage(ct, kt + 1, (ktg + 1) & 1);
      else if (ct < CTILES - 1) stage(ct + 1, 0, (ktg + 1) & 1);
      const _Float16* Ab = Asb + (ktg & 1) * 4096;
      const _Float16* Bb = Bsb + (ktg & 1) * 4096;
      half8 af[4], bf[4];
      #pragma unroll
      for (int r = 0; r < 4; ++r)
        af[r] = *(const half8*)&Ab[(wm * 64 + 16 * r + lx) * 32 + sw];
      #pragma unroll
      for (int c = 0; c < 4; ++c)
        bf[c] = *(const half8*)&Bb[(wn * 64 + 16 * c + lx) * 32 + sw];
      #pragma unroll
      for (int r = 0; r < 4; ++r)
        #pragma unroll
        for (int c = 0; c < 4; ++c)
          acc[r][c] = __builtin_amdgcn_mfma_f32_16x16x32_f16(
              af[r], bf[c], acc[r][c], 0, 0, 0);
    }
    // ---- Fold ct's col-tile into per-lane best (registers only).
    // j ascends with ct then c for fixed (row,lane): strict < keeps first j.
    const int colt0 = colbase + ct * 128;
    #pragma unroll
    for (int c = 0; c < 4; ++c) {
      int j = colt0 + wn * 64 + 16 * c + lx;
      float bq = bsq[j];
      #pragma unroll
      for (int r = 0; r < 4; ++r)
        #pragma unroll
        for (int reg = 0; reg < 4; ++reg) {
          float val = fmaf(-2.f, acc[r][c][reg], bq);
          int s = r * 4 + reg;
          if (val < bestv[s]) { bestv[s] = val; bestj[s] = j; }
          acc[r][c][reg] = 0.f;
        }
    }
  }

  // ---- Cross-lane lex-min via padded LDS. C/D layout: row = q*4 + reg. ----
  __syncthreads();  // all frag reads done before aliasing staging LDS
  #pragma unroll
  for (int s = 0; s < 16; ++s) {
    int r = s >> 2, reg = s & 3;
    int mrow = wm * 64 + 16 * r + 4 * q + reg;
    smem[(wn * 128 + mrow) * 17 + lx] = packkey(bestv[s], bestj[s]);
  }
  __syncthreads();
  if (t < 128) {
    unsigned long long best = ~0ull;
    #pragma unroll
    for (int w = 0; w < 2; ++w)
      #pragma unroll
      for (int x = 0; x < 16; ++x) {
        unsigned long long k = smem[(w * 128 + t) * 17 + x];
        if (k < best) best = k;
      }
    atomicMin(&packed[row0 + t], best);  // device-scope lex (val, idx) min
  }

  // ---- Last block of this row-strip decodes + writes outputs (NO fence;
  //      the barrier's vmcnt(0) guarantees our atomics are performed). ----
  __syncthreads();
  if (t == 0)
    flagp = (atomicAdd(&cnt[bx], 1) == NSTRIPB - 1);
  __syncthreads();
  if (flagp && t < 128) {
    int r = row0 + t;
    unsigned long long best = atomicMin(&packed[r], ~0ull);  // coherent read
    unsigned u = (unsigned)(best >> 32);
    u = (u & 0x80000000u) ? (u & 0x7fffffffu) : ~u;  // invert monotone map
    float dist = sqrtf(fmaxf(asq[r] + __uint_as_float(u), 0.f));
    int j = (int)(unsigned)(best & 0xffffffffu);
    out[r] = dist;
    float2 mi = {(float)r, (float)j};
    *(float2*)&out[NB1 + 2 * r] = mi;
  }
}

extern "C" void kernel_launch(void* const* d_in, const int* in_sizes, int n_in,
                              void* d_out, int out_size, void* d_ws, size_t ws_size,
                              hipStream_t stream) {
  const float* d1 = (const float*)d_in[0];
  const float* d2 = (const float*)d_in[1];
  float* out = (float*)d_out;

  char* w = (char*)d_ws;
  float* asq = (float*)w;                                   // 32 KB
  float* bsq = (float*)(w + 32768);                         // 32 KB
  _Float16* A2 = (_Float16*)(w + 65536);                    // 4 MB
  _Float16* B2 = (_Float16*)(w + 65536 + 4194304);          // 4 MB
  unsigned long long* packed =
      (unsigned long long*)(w + 65536 + 2 * 4194304);       // 64 KB
  int* cnt = (int*)(w + 65536 + 2 * 4194304 + 65536);       // 256 B

  convert_kernel<<<(NB1 + NB2) / 8, 256, 0, stream>>>(
      d1, d2, A2, B2, asq, bsq, packed, cnt);

  mfma_match_kernel<<<(NB1 / 128) * (NB2 / (128 * CTILES)), 256, 0, stream>>>(
      A2, B2, asq, bsq, packed, cnt, out);
}

// Round 9
// 127.780 us; speedup vs baseline: 1.4568x; 1.0114x over previous
//
#include <hip/hip_runtime.h>
#include <cstdint>

#define NB1 8192
#define NB2 8192
#define DDIM 128
#define KROW 256           // stored row: [hi(128) | lo(128)] f16
#define NKITER 12          // virtual K = 384 (hi*hi + lo*hi + hi*lo), BK=32
#define NSTRIPB (NB2 / 128)   // 64 blocks per row-strip

using half8   = __attribute__((ext_vector_type(8))) _Float16;
using half4   = __attribute__((ext_vector_type(4))) _Float16;
using float4v = __attribute__((ext_vector_type(4))) float;

typedef __attribute__((address_space(3))) void       lds_void;
typedef const __attribute__((address_space(1))) void glb_void;

__device__ inline unsigned long long packkey(float v, int j) {
  unsigned u = __float_as_uint(v);
  u = (u & 0x80000000u) ? ~u : (u | 0x80000000u);  // monotone float->uint
  return ((unsigned long long)u << 32) | (unsigned)j;
}

// virtual kt -> source 32-f16 chunk index within the [hi|lo] row
__device__ __forceinline__ int a_src(int kt) { return (kt < 8) ? kt : kt - 8; } // hi,lo,hi
__device__ __forceinline__ int b_src(int kt) { return (kt < 4) ? kt : kt - 4; } // hi,hi,lo

// ---------------------------------------------------------------------------
// Kernel 0: fp32 -> f16 hi/lo split + squared norms + init packed keys + cnt.
// One wave per 2 rows; float4 loads, half4 stores.
// ---------------------------------------------------------------------------
__global__ __launch_bounds__(256) void convert_kernel(
    const float* __restrict__ d1, const float* __restrict__ d2,
    _Float16* __restrict__ A2, _Float16* __restrict__ B2,
    float* __restrict__ asq, float* __restrict__ bsq,
    unsigned long long* __restrict__ packed, int* __restrict__ cnt) {
  int gid  = blockIdx.x * 256 + threadIdx.x;
  int wv   = gid >> 6;
  int lane = gid & 63;
  int rowc = 2 * wv + (lane >> 5);
  bool isA = rowc < NB1;
  const float* src = isA ? d1 : d2;
  int row = isA ? rowc : rowc - NB1;
  int k4  = (lane & 31) * 4;

  float4 v = *(const float4*)&src[row * DDIM + k4];
  _Float16 h0 = (_Float16)v.x, h1 = (_Float16)v.y;
  _Float16 h2 = (_Float16)v.z, h3 = (_Float16)v.w;
  half4 hh = {h0, h1, h2, h3};
  half4 ll = {(_Float16)(v.x - (float)h0), (_Float16)(v.y - (float)h1),
              (_Float16)(v.z - (float)h2), (_Float16)(v.w - (float)h3)};

  _Float16* dst = (isA ? A2 : B2) + (size_t)row * KROW;
  *(half4*)&dst[k4]       = hh;
  *(half4*)&dst[128 + k4] = ll;

  float s = v.x * v.x + v.y * v.y + v.z * v.z + v.w * v.w;
  #pragma unroll
  for (int off = 16; off > 0; off >>= 1) s += __shfl_xor(s, off, 64);
  if ((lane & 31) == 0) (isA ? asq : bsq)[row] = s;

  if (gid < NB1) packed[gid] = 0xFFFFFFFFFFFFFFFFull;  // +inf key
  if (gid < NB1 / 128) cnt[gid] = 0;                   // strip arrival counters
}

// ---------------------------------------------------------------------------
// Kernel 1: MFMA GEMM (virtual K=384 f16, fp32 acc) + fused argmin + output.
// EXACT R5 core (proven 67 us / 32% MfmaUtil / 0 conflicts / no spill):
// 128x128 tile, BK=32, 34816 B LDS dbuf, ~3 waves/SIMD.
// - Do NOT enlarge LDS (R6: 64 KB -> 2 blocks/CU -> 124 us).
// - Do NOT add per-lane best arrays (R8: 32 extra regs -> scratch spill,
//   WRITE_SIZE 45 MB -> 79 us). Epilogue folds straight from acc.
// - NO __threadfence in the tail (R7: per-block agent fence invalidates
//   per-XCD L2 -> 134 us). Ordering: atomicMin is a vm-op; __syncthreads
//   emits s_waitcnt vmcnt(0) per wave, so each block's mins are performed
//   at the coherent point before its cnt atomicAdd issues. Cross-block data
//   (packed, cnt) flows only through device-scope atomics. (Validated R8.)
// ---------------------------------------------------------------------------
__global__ __launch_bounds__(256, 3) void mfma_match_kernel(
    const _Float16* __restrict__ A2, const _Float16* __restrict__ B2,
    const float* __restrict__ asq, const float* __restrict__ bsq,
    unsigned long long* __restrict__ packed, int* __restrict__ cnt,
    float* __restrict__ out) {
  __shared__ unsigned long long smem[2 * 128 * 17];  // 34816 B, aliased
  __shared__ int flagp;
  _Float16* Asb = (_Float16*)smem;                   // 2 buffers x 4096 f16
  _Float16* Bsb = (_Float16*)smem + 8192;            // 2 buffers x 4096 f16

  const int t    = threadIdx.x;
  const int lane = t & 63;
  const int wid  = t >> 6;
  const int wm = wid >> 1, wn = wid & 1;
  const int lx = lane & 15, q = lane >> 4;

  // L2/XCD locality swizzle (dispatch round-robins id%8 across XCDs).
  const int id = blockIdx.x;
  const int xc = id & 7, kk = id >> 3;
  const int bx = ((kk >> 3) & 7) * 8 + xc;
  const int by = (kk & 7) + ((kk >> 6) & 7) * 8;
  const int row0 = bx * 128, col0 = by * 128;

  // Staging lane geometry. Slab = 16 rows x 4 cells(16B). Wave stages slabs
  // {2*wid, 2*wid+1}. Lane l -> row l>>2, LDS slot l&3; global chunk for that
  // slot is the inverse bank-swizzle: (slot - (row>>1)) & 3.
  const int sA   = wid * 2;
  const int rloc = lane >> 2;
  const int qch  = ((lane & 3) - (rloc >> 1)) & 3;
  const int rA0  = sA * 16 + rloc;
  const int kofs = qch * 8;

  float4v acc[4][4];
  #pragma unroll
  for (int r = 0; r < 4; ++r)
    #pragma unroll
    for (int c = 0; c < 4; ++c) acc[r][c] = (float4v){0.f, 0.f, 0.f, 0.f};

  float bq[4]; int jc[4];
  #pragma unroll
  for (int c = 0; c < 4; ++c) {
    jc[c] = col0 + wn * 64 + 16 * c + lx;
    bq[c] = bsq[jc[c]];
  }

  auto stage = [&](int kt, int buf) {
    const _Float16* ga =
        A2 + (size_t)(row0 + rA0) * KROW + a_src(kt) * 32 + kofs;
    __builtin_amdgcn_global_load_lds((glb_void*)ga,
        (lds_void*)(Asb + buf * 4096 + sA * 512), 16, 0, 0);
    __builtin_amdgcn_global_load_lds((glb_void*)(ga + 16 * KROW),
        (lds_void*)(Asb + buf * 4096 + (sA + 1) * 512), 16, 0, 0);
    const _Float16* gb =
        B2 + (size_t)(col0 + rA0) * KROW + b_src(kt) * 32 + kofs;
    __builtin_amdgcn_global_load_lds((glb_void*)gb,
        (lds_void*)(Bsb + buf * 4096 + sA * 512), 16, 0, 0);
    __builtin_amdgcn_global_load_lds((glb_void*)(gb + 16 * KROW),
        (lds_void*)(Bsb + buf * 4096 + (sA + 1) * 512), 16, 0, 0);
  };

  stage(0, 0);

  const int sw = ((q + (lx >> 1)) & 3) * 8;   // bank-swizzled chunk offset

  #pragma unroll
  for (int kt = 0; kt < NKITER; ++kt) {
    __syncthreads();  // stage(kt) drained (vmcnt0 before barrier); WAR safe
    if (kt < NKITER - 1) stage(kt + 1, (kt + 1) & 1);
    const _Float16* Ab = Asb + (kt & 1) * 4096;
    const _Float16* Bb = Bsb + (kt & 1) * 4096;
    half8 af[4], bf[4];
    #pragma unroll
    for (int r = 0; r < 4; ++r)
      af[r] = *(const half8*)&Ab[(wm * 64 + 16 * r + lx) * 32 + sw];
    #pragma unroll
    for (int c = 0; c < 4; ++c)
      bf[c] = *(const half8*)&Bb[(wn * 64 + 16 * c + lx) * 32 + sw];
    #pragma unroll
    for (int r = 0; r < 4; ++r)
      #pragma unroll
      for (int c = 0; c < 4; ++c)
        acc[r][c] = __builtin_amdgcn_mfma_f32_16x16x32_f16(
            af[r], bf[c], acc[r][c], 0, 0, 0);
  }

  // ---- Epilogue. C/D layout: col = lane&15, row = q*4 + reg. ----
  __syncthreads();  // all frag reads done before aliasing staging LDS
  #pragma unroll
  for (int r = 0; r < 4; ++r) {
    #pragma unroll
    for (int reg = 0; reg < 4; ++reg) {
      float bv = 1e30f; int bj = 0;
      #pragma unroll
      for (int c = 0; c < 4; ++c) {  // jc ascending -> strict < keeps min j
        float val = fmaf(-2.f, acc[r][c][reg], bq[c]);
        if (val < bv) { bv = val; bj = jc[c]; }
      }
      int mrow = wm * 64 + 16 * r + 4 * q + reg;
      smem[(wn * 128 + mrow) * 17 + lx] = packkey(bv, bj);
    }
  }
  __syncthreads();
  if (t < 128) {
    unsigned long long best = ~0ull;
    #pragma unroll
    for (int w = 0; w < 2; ++w)
      #pragma unroll
      for (int x = 0; x < 16; ++x) {
        unsigned long long k = smem[(w * 128 + t) * 17 + x];
        if (k < best) best = k;
      }
    atomicMin(&packed[row0 + t], best);  // device-scope lex (val, idx) min
  }

  // ---- Last block of this row-strip decodes + writes outputs (no fence). --
  __syncthreads();  // per-wave vmcnt(0): this block's atomics performed
  if (t == 0)
    flagp = (atomicAdd(&cnt[bx], 1) == NSTRIPB - 1);
  __syncthreads();
  if (flagp && t < 128) {
    int r = row0 + t;
    unsigned long long best = atomicMin(&packed[r], ~0ull);  // coherent read
    unsigned u = (unsigned)(best >> 32);
    u = (u & 0x80000000u) ? (u & 0x7fffffffu) : ~u;  // invert monotone map
    float dist = sqrtf(fmaxf(asq[r] + __uint_as_float(u), 0.f));
    int j = (int)(unsigned)(best & 0xffffffffu);
    out[r] = dist;
    float2 mi = {(float)r, (float)j};
    *(float2*)&out[NB1 + 2 * r] = mi;
  }
}

extern "C" void kernel_launch(void* const* d_in, const int* in_sizes, int n_in,
                              void* d_out, int out_size, void* d_ws, size_t ws_size,
                              hipStream_t stream) {
  const float* d1 = (const float*)d_in[0];
  const float* d2 = (const float*)d_in[1];
  float* out = (float*)d_out;

  char* w = (char*)d_ws;
  float* asq = (float*)w;                                   // 32 KB
  float* bsq = (float*)(w + 32768);                         // 32 KB
  _Float16* A2 = (_Float16*)(w + 65536);                    // 4 MB
  _Float16* B2 = (_Float16*)(w + 65536 + 4194304);          // 4 MB
  unsigned long long* packed =
      (unsigned long long*)(w + 65536 + 2 * 4194304);       // 64 KB
  int* cnt = (int*)(w + 65536 + 2 * 4194304 + 65536);       // 256 B

  convert_kernel<<<(NB1 + NB2) / 8, 256, 0, stream>>>(
      d1, d2, A2, B2, asq, bsq, packed, cnt);

  mfma_match_kernel<<<(NB1 / 128) * (NB2 / 128), 256, 0, stream>>>(
      A2, B2, asq, bsq, packed, cnt, out);
}